// Round 1
// baseline (213.091 us; speedup 1.0000x reference)
//
#include <hip/hip_runtime.h>
#include <hip/hip_bf16.h>

// GAT forward, MI355X. B=2,N=4096,F=256,O=64,H=4.
// k_h:   h = x@W (f32), w = h.a ; writes hT bf16 [B,H,O,N] + w f32 [B,H,N] to ws
// k_attn: flash-style softmax(leaky(w_i+w_j)+bias) @ h with bf16 MFMA PV.

constexpr int Bc = 2, Nc = 4096, Fc = 256, Oc = 64, Hc = 4;
constexpr float ALPHA = 0.2f;
constexpr float LOG2E = 1.4426950408889634f;

typedef __attribute__((ext_vector_type(8))) short bf16x8;
typedef __attribute__((ext_vector_type(4))) float f32x4;

static __device__ inline short f2bf(float x) {
    __hip_bfloat16 h = __float2bfloat16(x);
    return *reinterpret_cast<short*>(&h);
}

// ---------------- Kernel 1: per-head feature transform ----------------
// grid: B*H*(N/64) blocks, 256 threads. Thread computes 4n x 4o outputs.
__global__ __launch_bounds__(256) void k_h(const float* __restrict__ x,
                                           const float* __restrict__ W,
                                           const float* __restrict__ a,
                                           __hip_bfloat16* __restrict__ hT,
                                           float* __restrict__ wout) {
    __shared__ float xs[64][132];  // 64 rows x 128 f32 chunk, pad->132 (2-way max, free)
    const int nb = Nc / 64;
    const int blk = blockIdx.x;
    const int nt = blk % nb;
    const int bh = blk / nb;
    const int h = bh % Hc;
    const int b = bh / Hc;
    const int tid = threadIdx.x;
    const int o_id = tid & 15, n_id = tid >> 4;
    const int o0 = o_id * 4, n0 = n_id * 4;

    float acc[4][4] = {};

    for (int fs = 0; fs < Fc; fs += 128) {
        // stage x[64][128]
#pragma unroll
        for (int it = 0; it < 8; ++it) {
            int idx = it * 256 + tid;
            int r = idx >> 5, c = idx & 31;
            const float4 v = *reinterpret_cast<const float4*>(
                &x[((size_t)(b * Nc + nt * 64 + r)) * Fc + fs + c * 4]);
            *reinterpret_cast<float4*>(&xs[r][c * 4]) = v;
        }
        __syncthreads();
        for (int f = 0; f < 128; ++f) {
            const float4 wv = *reinterpret_cast<const float4*>(
                &W[((size_t)(h * Fc + fs + f)) * Oc + o0]);
            float xv[4];
#pragma unroll
            for (int r = 0; r < 4; ++r) xv[r] = xs[n0 + r][f];
#pragma unroll
            for (int r = 0; r < 4; ++r) {
                acc[r][0] = __builtin_fmaf(xv[r], wv.x, acc[r][0]);
                acc[r][1] = __builtin_fmaf(xv[r], wv.y, acc[r][1]);
                acc[r][2] = __builtin_fmaf(xv[r], wv.z, acc[r][2]);
                acc[r][3] = __builtin_fmaf(xv[r], wv.w, acc[r][3]);
            }
        }
        __syncthreads();
    }

    // w = h . a  (reduce across the 16 o_id lanes; they are consecutive lanes)
    const float4 av = *reinterpret_cast<const float4*>(&a[h * Oc + o0]);
    float part[4];
#pragma unroll
    for (int r = 0; r < 4; ++r) {
        part[r] = acc[r][0] * av.x + acc[r][1] * av.y + acc[r][2] * av.z +
                  acc[r][3] * av.w;
#pragma unroll
        for (int off = 1; off < 16; off <<= 1)
            part[r] += __shfl_xor(part[r], off, 64);
    }
    const int n_glob = nt * 64 + n0;
    if (o_id == 0) {
#pragma unroll
        for (int r = 0; r < 4; ++r)
            wout[((size_t)(b * Hc + h)) * Nc + n_glob + r] = part[r];
    }
    // hT[b][h][o][n] bf16 (transposed for MFMA B-fragment contiguity)
#pragma unroll
    for (int r = 0; r < 4; ++r)
#pragma unroll
        for (int c = 0; c < 4; ++c)
            hT[((size_t)(b * Hc + h) * Oc + o0 + c) * Nc + n_glob + r] =
                __float2bfloat16(acc[r][c]);
}

// ---------------- Kernel 2: fused attention ----------------
// grid: B*(N/16) blocks, 256 threads = 4 waves, wave = head.
__global__ __launch_bounds__(256) void k_attn(const float* __restrict__ bias,
                                              const float* __restrict__ bvec,
                                              const float* __restrict__ wrow,
                                              const __hip_bfloat16* __restrict__ hT,
                                              float* __restrict__ out) {
    __shared__ float hsum[4][16][64];  // 16 KB
    const int blk = blockIdx.x;
    const int b = blk / (Nc / 16);
    const int i0 = (blk % (Nc / 16)) * 16;
    const int tid = threadIdx.x;
    const int hd = tid >> 6;
    const int lane = tid & 63;
    const int li = lane & 15, lg = lane >> 4;

    const float wi = wrow[((size_t)(b * Hc + hd)) * Nc + i0 + li];
    const float* __restrict__ wj_base = &wrow[((size_t)(b * Hc + hd)) * Nc];
    const float* __restrict__ bias_row = &bias[((size_t)b * Nc + (i0 + li)) * Nc];
    const __hip_bfloat16* __restrict__ hTh = &hT[((size_t)(b * Hc + hd)) * Oc * Nc];

    f32x4 acc[4] = {{0.f, 0.f, 0.f, 0.f},
                    {0.f, 0.f, 0.f, 0.f},
                    {0.f, 0.f, 0.f, 0.f},
                    {0.f, 0.f, 0.f, 0.f}};
    float m_run = -1e30f, l_run = 0.f;

    for (int j0 = 0; j0 < Nc; j0 += 64) {
        float s[16];
#pragma unroll
        for (int sub = 0; sub < 2; ++sub) {
            const int jl = j0 + sub * 32 + lg * 8;
            const float4 bv0 = *reinterpret_cast<const float4*>(&bias_row[jl]);
            const float4 bv1 = *reinterpret_cast<const float4*>(&bias_row[jl + 4]);
            const float4 wj0 = *reinterpret_cast<const float4*>(&wj_base[jl]);
            const float4 wj1 = *reinterpret_cast<const float4*>(&wj_base[jl + 4]);
            const float vj[8] = {wj0.x, wj0.y, wj0.z, wj0.w,
                                 wj1.x, wj1.y, wj1.z, wj1.w};
            const float bb[8] = {bv0.x, bv0.y, bv0.z, bv0.w,
                                 bv1.x, bv1.y, bv1.z, bv1.w};
#pragma unroll
            for (int t = 0; t < 8; ++t) {
                const float v = wi + vj[t];
                const float lv = fmaxf(v, ALPHA * v);  // leaky_relu, alpha<1
                s[sub * 8 + t] = lv + bb[t];
            }
        }
        // row max over the 64 j of this tile (row li lives in lanes li+16k)
        float mx = s[0];
#pragma unroll
        for (int t = 1; t < 16; ++t) mx = fmaxf(mx, s[t]);
        mx = fmaxf(mx, __shfl_xor(mx, 16, 64));
        mx = fmaxf(mx, __shfl_xor(mx, 32, 64));
        const float m_new = fmaxf(m_run, mx);
        const float scale = __builtin_amdgcn_exp2f((m_run - m_new) * LOG2E);
        const float mL = m_new * LOG2E;
        float p[16];
        float tsum = 0.f;
#pragma unroll
        for (int t = 0; t < 16; ++t) {
            p[t] = __builtin_amdgcn_exp2f(__builtin_fmaf(s[t], LOG2E, -mL));
            tsum += p[t];
        }
        tsum += __shfl_xor(tsum, 16, 64);
        tsum += __shfl_xor(tsum, 32, 64);
        l_run = l_run * scale + tsum;
        m_run = m_new;
        // rescale accumulators (C rows are lg*4+r)
        float sc[4];
#pragma unroll
        for (int r = 0; r < 4; ++r) sc[r] = __shfl(scale, lg * 4 + r, 64);
#pragma unroll
        for (int of = 0; of < 4; ++of) {
            acc[of][0] *= sc[0];
            acc[of][1] *= sc[1];
            acc[of][2] *= sc[2];
            acc[of][3] *= sc[3];
        }
        // P fragments (A layout: row=li, 8 contiguous j per lane-group)
        bf16x8 pa[2];
#pragma unroll
        for (int sub = 0; sub < 2; ++sub)
#pragma unroll
            for (int t = 0; t < 8; ++t) pa[sub][t] = f2bf(p[sub * 8 + t]);
        // V fragments straight from hT (B layout: col=li, same 8 contiguous j)
#pragma unroll
        for (int of = 0; of < 4; ++of) {
#pragma unroll
            for (int sub = 0; sub < 2; ++sub) {
                const bf16x8 vb = *reinterpret_cast<const bf16x8*>(
                    &hTh[((size_t)(of * 16 + li)) * Nc + j0 + sub * 32 + lg * 8]);
                acc[of] = __builtin_amdgcn_mfma_f32_16x16x32_bf16(pa[sub], vb,
                                                                  acc[of], 0, 0, 0);
            }
        }
    }

    // epilogue: normalize rows, average heads, add mean bias vector
    float linv[4];
#pragma unroll
    for (int r = 0; r < 4; ++r) linv[r] = 1.0f / __shfl(l_run, lg * 4 + r, 64);
#pragma unroll
    for (int of = 0; of < 4; ++of)
#pragma unroll
        for (int r = 0; r < 4; ++r)
            hsum[hd][lg * 4 + r][of * 16 + li] = acc[of][r] * linv[r];
    __syncthreads();
#pragma unroll
    for (int k = 0; k < 4; ++k) {
        const int e = k * 256 + tid;
        const int row = e >> 6, col = e & 63;
        const float ssum = hsum[0][row][col] + hsum[1][row][col] +
                           hsum[2][row][col] + hsum[3][row][col];
        const float bm = 0.25f * (bvec[col] + bvec[Oc + col] + bvec[2 * Oc + col] +
                                  bvec[3 * Oc + col]);
        out[((size_t)(b * Nc + i0 + row)) * Oc + col] = 0.25f * ssum + bm;
    }
}

extern "C" void kernel_launch(void* const* d_in, const int* in_sizes, int n_in,
                              void* d_out, int out_size, void* d_ws, size_t ws_size,
                              hipStream_t stream) {
    const float* x = (const float*)d_in[0];     // [B,N,F]
    const float* bias = (const float*)d_in[1];  // [B,N,N]
    const float* W = (const float*)d_in[2];     // [H,F,O]
    const float* a = (const float*)d_in[3];     // [H,O]
    const float* bvec = (const float*)d_in[4];  // [H,O]
    float* out = (float*)d_out;                 // [B,N,O]

    __hip_bfloat16* hT = (__hip_bfloat16*)d_ws;               // B*H*O*N bf16 = 4 MB
    float* wbuf = (float*)((char*)d_ws + (size_t)Bc * Hc * Oc * Nc * 2);  // B*H*N f32

    k_h<<<Bc * Hc * (Nc / 64), 256, 0, stream>>>(x, W, a, hT, wbuf);
    k_attn<<<Bc * (Nc / 16), 256, 0, stream>>>(bias, bvec, wbuf, hT, out);
}